// Round 14
// baseline (461.309 us; speedup 1.0000x reference)
//
#include <hip/hip_runtime.h>
#include <hip/hip_bf16.h>
#include <cstdint>
#include <cstddef>

#define BB 8
#define NHH 8
#define NQ 3137      // 56*56+1
#define NKV 785      // 28*28+1
#define HDIM 64
#define AUG 128      // augmented channel count (64 q/k + 28 h + 28 w + 8 pad)
#define MROWS (BB*NQ)   // 25096
#define SCALE 0.125f
#define VTP 832         // padded v^T row length

typedef unsigned short ushort_t;
typedef __attribute__((ext_vector_type(8))) short s16x8;   // 8 bf16 (4 VGPR)
typedef __attribute__((ext_vector_type(4))) float f32x4;
typedef __attribute__((ext_vector_type(16))) float f32x16;

__device__ __forceinline__ float bf2f(ushort_t u) {
  union { unsigned int i; float f; } v; v.i = ((unsigned int)u) << 16; return v.f;
}
__device__ __forceinline__ ushort_t f2bf(float f) {
  union { float f; unsigned int i; } v; v.f = f;
  unsigned int r = v.i + 0x7fffu + ((v.i >> 16) & 1u);   // RNE
  return (ushort_t)(r >> 16);
}
__device__ __forceinline__ unsigned int cvt_pk_bf16(float lo, float hi) {
  unsigned int r;
  asm("v_cvt_pk_bf16_f32 %0, %1, %2" : "=v"(r) : "v"(lo), "v"(hi));
  return r;
}
// swizzled 16B fragment read, 128B rows (8 slots)
__device__ __forceinline__ s16x8 lds_frag8(const ushort_t* base, int row, int slot) {
  const char* p = (const char*)base + row * 128 + (((slot ^ (row & 7)) & 7) << 4);
  return *(const s16x8*)p;
}
// swizzled 16B fragment read, 256B rows (16 slots)
__device__ __forceinline__ s16x8 lds_frag16(const ushort_t* base, int row, int slot) {
  const char* p = (const char*)base + row * 256 + (((slot ^ (row & 15)) & 15) << 4);
  return *(const s16x8*)p;
}

// ---------------------------------------------------------------------------
// f32 -> bf16 cast, 4 elems/thread (all sizes are multiples of 4)
// ---------------------------------------------------------------------------
__global__ __launch_bounds__(256) void cast_bf16_kernel(
    const float* __restrict__ in, ushort_t* __restrict__ outp, int n4) {
  const int i = blockIdx.x * 256 + threadIdx.x;
  if (i >= n4) return;
  const float4 v = ((const float4*)in)[i];
  uint2 o;
  o.x = cvt_pk_bf16(v.x, v.y);
  o.y = cvt_pk_bf16(v.z, v.w);
  *(uint2*)(outp + (size_t)i * 4) = o;
}

// ---------------------------------------------------------------------------
// bf16 MFMA GEMM with global_load_lds staging.  BM=128, BN=256, BK=64,
// 512 threads (8 waves of 64x64).  Halves A re-reads vs BN=128.
// EPI 0: bf16 scatter into qkv_raw[(which,b,y,tok,c)].  EPI 1: f32 store.
// ---------------------------------------------------------------------------
template<int EPI>
__global__ __launch_bounds__(512) void mfma_gemm_glds(
    const ushort_t* __restrict__ A, const ushort_t* __restrict__ W,
    const float* __restrict__ bias, void* __restrict__ outp, int M) {
  __shared__ ushort_t As[128 * 64];   // 16 KB (128 rows x 128B)
  __shared__ ushort_t Bs[256 * 64];   // 32 KB (256 rows x 128B)
  const int tid = threadIdx.x;
  const int l = tid & 63, w = tid >> 6;     // 8 waves
  const int wr = w >> 2, wc = w & 3;        // 2 x 4 wave grid
  const int lrow = l & 15, lk = l >> 4;
  const int m0 = blockIdx.y * 128, n0 = blockIdx.x * 256;
  f32x4 acc[4][4];
  #pragma unroll
  for (int i = 0; i < 4; ++i) {
    #pragma unroll
    for (int j = 0; j < 4; ++j) acc[i][j] = (f32x4){0.f, 0.f, 0.f, 0.f};
  }
  for (int k0 = 0; k0 < 512; k0 += 64) {
    __syncthreads();   // previous k-step's frag reads done
    // A: 1024 slots (2 calls), B: 2048 slots (4 calls); slot = c*512+w*64+l
    #pragma unroll
    for (int c = 0; c < 2; ++c) {
      const int r = c * 64 + w * 8 + (l >> 3);
      int mA = m0 + r; if (mA > M - 1) mA = M - 1;
      const int sch = ((l & 7) ^ (r & 7)) * 8;
      const ushort_t* src = A + (size_t)mA * 512 + k0 + sch;
      __builtin_amdgcn_global_load_lds((void*)src,
          (void*)(As + (size_t)(c * 512 + w * 64) * 8), 16, 0, 0);
    }
    #pragma unroll
    for (int c = 0; c < 4; ++c) {
      const int r = c * 64 + w * 8 + (l >> 3);
      const int sch = ((l & 7) ^ (r & 7)) * 8;
      const ushort_t* src = W + (size_t)(n0 + r) * 512 + k0 + sch;
      __builtin_amdgcn_global_load_lds((void*)src,
          (void*)(Bs + (size_t)(c * 512 + w * 64) * 8), 16, 0, 0);
    }
    __syncthreads();   // drains vmcnt(0); tile published
    #pragma unroll
    for (int sub = 0; sub < 2; ++sub) {
      s16x8 af[4], bfr[4];
      #pragma unroll
      for (int mi = 0; mi < 4; ++mi) {
        const int r = wr * 64 + mi * 16 + lrow;
        const int slot = (sub * 4 + lk) ^ (r & 7);
        af[mi] = *(const s16x8*)(As + r * 64 + slot * 8);
      }
      #pragma unroll
      for (int ni = 0; ni < 4; ++ni) {
        const int r = wc * 64 + ni * 16 + lrow;
        const int slot = (sub * 4 + lk) ^ (r & 7);
        bfr[ni] = *(const s16x8*)(Bs + r * 64 + slot * 8);
      }
      #pragma unroll
      for (int mi = 0; mi < 4; ++mi) {
        #pragma unroll
        for (int ni = 0; ni < 4; ++ni)
          acc[mi][ni] = __builtin_amdgcn_mfma_f32_16x16x32_bf16(
              af[mi], bfr[ni], acc[mi][ni], 0, 0, 0);
      }
    }
  }
  #pragma unroll
  for (int mi = 0; mi < 4; ++mi) {
    #pragma unroll
    for (int r = 0; r < 4; ++r) {
      const int m = m0 + wr * 64 + mi * 16 + 4 * lk + r;
      if (m >= M) continue;
      #pragma unroll
      for (int ni = 0; ni < 4; ++ni) {
        const int n = n0 + wc * 64 + ni * 16 + lrow;
        const float v = acc[mi][ni][r] + bias[n];
        if (EPI == 0) {
          const int which = n >> 9, y = (n >> 6) & 7, c = n & 63;
          const int b_ = m / NQ, tok = m - b_ * NQ;
          ((ushort_t*)outp)[((((size_t)which * BB + b_) * NHH + y) * NQ + tok) * HDIM + c] = f2bf(v);
        } else {
          ((float*)outp)[(size_t)m * 512 + n] = v;
        }
      }
    }
  }
}

// ---------------------------------------------------------------------------
// Depthwise 3x3 pool + LayerNorm over HD=64.  MODE 0: plain bf16 row (v).
// MODE 1: q -> q_bf (unscaled) + qaug[0:64]=q*SCALE, [64:128]=0.
// MODE 2: k -> kaug[0:64]=k, [64:120]=one-hot(kh,kw), [120:128]=0.
// ---------------------------------------------------------------------------
template<int MODE>
__global__ __launch_bounds__(256) void pool_ln_kernel(
    const ushort_t* __restrict__ in, ushort_t* __restrict__ out0,
    ushort_t* __restrict__ out1,
    const float* __restrict__ cw, const float* __restrict__ lnw,
    const float* __restrict__ lnb, int stride, int OW, int R) {
  const int tid = threadIdx.x;
  const int c = tid & 63;
  const int rid = blockIdx.x * 4 + (tid >> 6);
  const int by = rid / R;
  const int n = rid - by * R;
  const ushort_t* ibase = in + (size_t)by * NQ * HDIM;
  float val;
  if (n == 0) {
    val = bf2f(ibase[c]);
  } else {
    const int p = n - 1;
    const int ho = p / OW, wo = p - ho * OW;
    float s = 0.f;
    #pragma unroll
    for (int dh = 0; dh < 3; ++dh) {
      const int hh = ho * stride + dh - 1;
      if (hh < 0 || hh >= 56) continue;
      #pragma unroll
      for (int dw = 0; dw < 3; ++dw) {
        const int ww = wo * stride + dw - 1;
        if (ww < 0 || ww >= 56) continue;
        s += cw[c * 9 + dh * 3 + dw] * bf2f(ibase[(size_t)(1 + hh * 56 + ww) * HDIM + c]);
      }
    }
    val = s;
  }
  float sum = val, sq = val * val;
  #pragma unroll
  for (int off = 32; off > 0; off >>= 1) {
    sum += __shfl_xor(sum, off);
    sq  += __shfl_xor(sq,  off);
  }
  const float mean = sum * (1.f / 64.f);
  const float var  = sq * (1.f / 64.f) - mean * mean;
  const float rs = rsqrtf(var + 1e-6f);
  const float lno = (val - mean) * rs * lnw[c] + lnb[c];
  if (MODE == 0) {
    out0[(size_t)rid * HDIM + c] = f2bf(lno);
  } else if (MODE == 1) {
    out0[(size_t)rid * HDIM + c] = f2bf(lno);
    out1[(size_t)rid * AUG + c] = f2bf(lno * SCALE);
    out1[(size_t)rid * AUG + 64 + c] = 0;
  } else {
    out0[(size_t)rid * AUG + c] = f2bf(lno);
    ushort_t aug = 0;
    if (n >= 1) {
      const int p = n - 1;
      const int kh = p / 28, kw = p - 28 * kh;
      if (c < 28) { if (c == kh) aug = 0x3F80; }
      else if (c < 56) { if (c - 28 == kw) aug = 0x3F80; }
    }
    out0[(size_t)rid * AUG + 64 + c] = aug;
  }
}

// ---------------------------------------------------------------------------
// V (row-major per head) -> V^T (64 channels x VTP cols), zero-padded cols.
// ---------------------------------------------------------------------------
__global__ __launch_bounds__(256) void transpose_v_kernel(
    const ushort_t* __restrict__ vin, ushort_t* __restrict__ vtout) {
  __shared__ ushort_t T[64][65];
  const int tid = threadIdx.x;
  const int by = blockIdx.y;
  const int n0 = blockIdx.x * 64;
  #pragma unroll
  for (int half = 0; half < 2; ++half) {
    const int idx = tid + half * 256;
    const int r = idx >> 3, s = idx & 7;
    const int n = n0 + r;
    uint4 d = make_uint4(0u, 0u, 0u, 0u);
    if (n < NKV) d = *(const uint4*)(vin + ((size_t)by * NKV + n) * HDIM + s * 8);
    const ushort_t* dp = (const ushort_t*)&d;
    #pragma unroll
    for (int e = 0; e < 8; ++e) T[r][s * 8 + e] = dp[e];
  }
  __syncthreads();
  #pragma unroll
  for (int half = 0; half < 2; ++half) {
    const int idx = tid + half * 256;
    const int c = idx >> 3, g = idx & 7;
    ushort_t pk[8];
    #pragma unroll
    for (int e = 0; e < 8; ++e) pk[e] = T[g * 8 + e][c];
    *(uint4*)(vtout + ((size_t)by * 64 + c) * VTP + n0 + g * 8) = *(const uint4*)pk;
  }
}

// ---------------------------------------------------------------------------
// MFMA rel-bias -> scatter bf16 directly into qaug channels 64+mode*28+kh.
// ---------------------------------------------------------------------------
__global__ __launch_bounds__(256) void relbias_mfma_kernel(
    const ushort_t* __restrict__ qb, const float* __restrict__ rph,
    const float* __restrict__ rpw, ushort_t* __restrict__ qaug) {
  const int tid = threadIdx.x;
  const int l = tid & 63, w = tid >> 6;
  const int lrow = l & 15, lk = l >> 4;
  const int hw = blockIdx.y;
  const int mode = blockIdx.z;
  const int r0 = blockIdx.x * 256 + w * 64;
  const float* tab = mode ? rpw : rph;
  s16x8 bfr[2][2];
  #pragma unroll
  for (int ni = 0; ni < 2; ++ni) {
    const int kh = ni * 16 + lrow;
    int trow = hw - 2 * kh + 54;
    if (trow < 0) trow = 0;
    const float* tr = tab + (size_t)trow * 64 + lk * 8;
    #pragma unroll
    for (int k0 = 0; k0 < 2; ++k0) {
      const float4 t0 = *(const float4*)(tr + k0 * 32);
      const float4 t1 = *(const float4*)(tr + k0 * 32 + 4);
      s16x8 bb;
      bb[0] = (short)f2bf(t0.x); bb[1] = (short)f2bf(t0.y);
      bb[2] = (short)f2bf(t0.z); bb[3] = (short)f2bf(t0.w);
      bb[4] = (short)f2bf(t1.x); bb[5] = (short)f2bf(t1.y);
      bb[6] = (short)f2bf(t1.z); bb[7] = (short)f2bf(t1.w);
      bfr[ni][k0] = bb;
    }
  }
  s16x8 af[4][2];
  #pragma unroll
  for (int mi = 0; mi < 4; ++mi) {
    const int rA = r0 + mi * 16 + lrow;
    const int by = rA / 56, oth = rA - 56 * by;
    const int tok = mode ? (1 + oth * 56 + hw) : (1 + hw * 56 + oth);
    const ushort_t* qp = qb + ((size_t)by * NQ + tok) * HDIM + lk * 8;
    af[mi][0] = *(const s16x8*)(qp);
    af[mi][1] = *(const s16x8*)(qp + 32);
  }
  f32x4 acc[4][2];
  #pragma unroll
  for (int mi = 0; mi < 4; ++mi) {
    #pragma unroll
    for (int ni = 0; ni < 2; ++ni) acc[mi][ni] = (f32x4){0.f, 0.f, 0.f, 0.f};
  }
  #pragma unroll
  for (int k0 = 0; k0 < 2; ++k0) {
    #pragma unroll
    for (int mi = 0; mi < 4; ++mi) {
      #pragma unroll
      for (int ni = 0; ni < 2; ++ni)
        acc[mi][ni] = __builtin_amdgcn_mfma_f32_16x16x32_bf16(
            af[mi][k0], bfr[ni][k0], acc[mi][ni], 0, 0, 0);
    }
  }
  const int augofs = 64 + mode * 28;
  #pragma unroll
  for (int mi = 0; mi < 4; ++mi) {
    #pragma unroll
    for (int r = 0; r < 4; ++r) {
      const int row = r0 + mi * 16 + 4 * lk + r;
      const int by = row / 56, oth = row - 56 * by;
      const int tok = 1 + (mode ? (oth * 56 + hw) : (hw * 56 + oth));
      ushort_t* orow = qaug + ((size_t)by * NQ + tok) * AUG + augofs;
      #pragma unroll
      for (int ni = 0; ni < 2; ++ni) {
        const int kh = ni * 16 + lrow;
        if (kh < 28) orow[kh] = f2bf(acc[mi][ni][r]);
      }
    }
  }
}

// ---------------------------------------------------------------------------
// Flash attention (r12-proven, 148us): glds double-buffered K/V staging,
// ONE barrier per k-tile.  32x32 MFMA swapped, bias via aug channels,
// defer-max + tree reductions, in-place exp.
// ---------------------------------------------------------------------------
__global__ __launch_bounds__(256) void attn_mfma32_kernel(
    const ushort_t* __restrict__ qaug, const ushort_t* __restrict__ kaug,
    const ushort_t* __restrict__ qb, const ushort_t* __restrict__ vt,
    ushort_t* __restrict__ outp) {
  __shared__ ushort_t Kl[2][64 * 128];   // 2 x 16 KB (64 rows x 256B)
  __shared__ ushort_t Vl[2][64 * 64];    // 2 x 8 KB  (64 rows x 128B)
  const int tid = threadIdx.x;
  const int l = tid & 63, w = tid >> 6;
  const int h = l >> 5, q5 = l & 31;
  const int by = blockIdx.y;
  const int qt0 = blockIdx.x * 128;
  const int qloc = w * 32 + q5;
  const int qglob = qt0 + qloc;
  const int qcl = qglob < NQ ? qglob : NQ - 1;
  const ushort_t* qrow = qaug + ((size_t)by * NQ + qcl) * AUG;
  s16x8 qf[8];
  #pragma unroll
  for (int cb = 0; cb < 8; ++cb)
    qf[cb] = *(const s16x8*)(qrow + cb * 16 + h * 8);
  f32x16 ot0, ot1;
  #pragma unroll
  for (int i = 0; i < 16; ++i) { ot0[i] = 0.f; ot1[i] = 0.f; }
  float mr = -1e30f, lr = 0.f;
  const ushort_t* kab = kaug + (size_t)by * NKV * AUG;
  const ushort_t* vtb = vt + (size_t)by * 64 * VTP;
  const int krloc = l >> 4;                 // 0..3
  const int vrloc = l >> 3;                 // 0..7
  auto issue_tile = [&](int it_, int buf) {
    const int j0 = it_ * 64;
    ushort_t* Kb = &Kl[buf][0];
    ushort_t* Vb = &Vl[buf][0];
    #pragma unroll
    for (int jj = 0; jj < 4; ++jj) {
      const int r0 = w * 16 + jj * 4;
      const int rloc = r0 + krloc;
      int jg = j0 + rloc; if (jg > NKV - 1) jg = NKV - 1;
      const int sch = ((l & 15) ^ (rloc & 15)) * 8;
      const ushort_t* src = kab + (size_t)jg * AUG + sch;
      __builtin_amdgcn_global_load_lds((void*)src, (void*)(Kb + r0 * 128), 16, 0, 0);
    }
    #pragma unroll
    for (int jj = 0; jj < 2; ++jj) {
      const int r0 = w * 16 + jj * 8;
      const int crow = r0 + vrloc;
      const int sch = ((l & 7) ^ (crow & 7)) * 8;
      const ushort_t* src = vtb + (size_t)crow * VTP + j0 + sch;
      __builtin_amdgcn_global_load_lds((void*)src, (void*)(Vb + r0 * 64), 16, 0, 0);
    }
  };
  issue_tile(0, 0);
  __syncthreads();
  #pragma unroll 1
  for (int it = 0; it < 13; ++it) {
    const int cur = it & 1;
    const ushort_t* Kc = &Kl[cur][0];
    const ushort_t* Vc = &Vl[cur][0];
    if (it < 12) issue_tile(it + 1, cur ^ 1);
    f32x16 st0, st1;
    #pragma unroll
    for (int i = 0; i < 16; ++i) { st0[i] = 0.f; st1[i] = 0.f; }
    __builtin_amdgcn_s_setprio(1);
    #pragma unroll
    for (int cb = 0; cb < 8; ++cb) {
      st0 = __builtin_amdgcn_mfma_f32_32x32x16_bf16(
          lds_frag16(Kc, q5, cb * 2 + h), qf[cb], st0, 0, 0, 0);
      st1 = __builtin_amdgcn_mfma_f32_32x32x16_bf16(
          lds_frag16(Kc, 32 + q5, cb * 2 + h), qf[cb], st1, 0, 0, 0);
    }
    __builtin_amdgcn_s_setprio(0);
    if (it == 12) {
      #pragma unroll
      for (int r = 0; r < 16; ++r) {
        const int klocal = (r & 3) + 8 * (r >> 2) + 4 * h;
        if (768 + klocal >= NKV) st0[r] = -1e30f;
        st1[r] = -1e30f;
      }
    }
    float tm[16];
    #pragma unroll
    for (int r = 0; r < 16; ++r) tm[r] = fmaxf(st0[r], st1[r]);
    #pragma unroll
    for (int s = 8; s > 0; s >>= 1) {
      #pragma unroll
      for (int r = 0; r < 8; ++r)
        if (r < s) tm[r] = fmaxf(tm[r], tm[r + s]);
    }
    float mloc = fmaxf(tm[0], __shfl_xor(tm[0], 32));
    if (!__all(mloc <= mr + 8.f)) {
      const float mn = fmaxf(mr, mloc);
      const float sc = __expf(mr - mn);
      mr = mn;
      lr *= sc;
      #pragma unroll
      for (int i = 0; i < 16; ++i) { ot0[i] *= sc; ot1[i] *= sc; }
    }
    float ts[16];
    #pragma unroll
    for (int r = 0; r < 16; ++r) {
      st0[r] = __expf(st0[r] - mr);
      st1[r] = __expf(st1[r] - mr);
      ts[r] = st0[r] + st1[r];
    }
    #pragma unroll
    for (int s = 8; s > 0; s >>= 1) {
      #pragma unroll
      for (int r = 0; r < 8; ++r)
        if (r < s) ts[r] += ts[r + s];
    }
    lr += ts[0] + __shfl_xor(ts[0], 32);
    auto pvstep = [&](const f32x16& pv, int kt) {
      #pragma unroll
      for (int kbk = 0; kbk < 2; ++kbk) {
        const unsigned int pk01 = cvt_pk_bf16(pv[kbk * 8 + 0], pv[kbk * 8 + 1]);
        const unsigned int pk23 = cvt_pk_bf16(pv[kbk * 8 + 2], pv[kbk * 8 + 3]);
        const unsigned int pk45 = cvt_pk_bf16(pv[kbk * 8 + 4], pv[kbk * 8 + 5]);
        const unsigned int pk67 = cvt_pk_bf16(pv[kbk * 8 + 6], pv[kbk * 8 + 7]);
        const unsigned int sA = (unsigned int)__shfl_xor((int)pk01, 32);
        const unsigned int sB = (unsigned int)__shfl_xor((int)pk45, 32);
        const unsigned int sC = (unsigned int)__shfl_xor((int)pk23, 32);
        const unsigned int sD = (unsigned int)__shfl_xor((int)pk67, 32);
        int4 fw;
        fw.x = (int)(h ? sB : pk01);
        fw.y = (int)(h ? sD : pk23);
        fw.z = (int)(h ? pk45 : sA);
        fw.w = (int)(h ? pk67 : sC);
        s16x8 pf;
        __builtin_memcpy(&pf, &fw, 16);
        const int slot = kt * 4 + kbk * 2 + h;
        __builtin_amdgcn_s_setprio(1);
        ot0 = __builtin_amdgcn_mfma_f32_32x32x16_bf16(
            lds_frag8(Vc, q5, slot), pf, ot0, 0, 0, 0);
        ot1 = __builtin_amdgcn_mfma_f32_32x32x16_bf16(
            lds_frag8(Vc, 32 + q5, slot), pf, ot1, 0, 0, 0);
        __builtin_amdgcn_s_setprio(0);
      }
    };
    pvstep(st0, 0);
    pvstep(st1, 1);
    __syncthreads();
  }
  const float inv = 1.f / lr;
  if (qglob < NQ) {
    const int b_ = by >> 3, y_ = by & 7;
    ushort_t* obase = outp + ((size_t)b_ * NQ + qglob) * 512 + (size_t)y_ * 64;
    const ushort_t* rbase = qb + ((size_t)by * NQ + qglob) * HDIM;
    #pragma unroll
    for (int ch = 0; ch < 2; ++ch) {
      #pragma unroll
      for (int rg = 0; rg < 4; ++rg) {
        const int c0 = ch * 32 + 8 * rg + 4 * h;
        float vv[4];
        #pragma unroll
        for (int e = 0; e < 4; ++e)
          vv[e] = (ch ? ot1[rg * 4 + e] : ot0[rg * 4 + e]) * inv;
        if (qglob > 0) {
          #pragma unroll
          for (int e = 0; e < 4; ++e) vv[e] += bf2f(rbase[c0 + e]);
        }
        ushort_t pk[4] = { f2bf(vv[0]), f2bf(vv[1]), f2bf(vv[2]), f2bf(vv[3]) };
        *(uint2*)(obase + c0) = *(const uint2*)pk;
      }
    }
  }
}

// ---------------------------------------------------------------------------
extern "C" void kernel_launch(void* const* d_in, const int* in_sizes, int n_in,
                              void* d_out, int out_size, void* d_ws, size_t ws_size,
                              hipStream_t stream) {
  const float* x        = (const float*)d_in[0];
  const float* qkv_w    = (const float*)d_in[1];
  const float* qkv_b    = (const float*)d_in[2];
  const float* proj_w   = (const float*)d_in[3];
  const float* proj_b   = (const float*)d_in[4];
  const float* pool_q_w = (const float*)d_in[5];
  const float* pool_k_w = (const float*)d_in[6];
  const float* pool_v_w = (const float*)d_in[7];
  const float* lnq_w    = (const float*)d_in[8];
  const float* lnq_b    = (const float*)d_in[9];
  const float* lnk_w    = (const float*)d_in[10];
  const float* lnk_b    = (const float*)d_in[11];
  const float* lnv_w    = (const float*)d_in[12];
  const float* lnv_b    = (const float*)d_in[13];
  const float* rel_pos_h = (const float*)d_in[14];
  const float* rel_pos_w = (const float*)d_in[15];

  constexpr size_t E1 = (size_t)BB * NHH * NQ * HDIM;   // 12,849,152
  char* ws = (char*)d_ws;
  size_t off = 0;
  ushort_t* x_bf     = (ushort_t*)(ws + off); off += (size_t)MROWS * 512 * 2;
  ushort_t* qkvw_bf  = (ushort_t*)(ws + off); off += (size_t)1536 * 512 * 2;
  ushort_t* projw_bf = (ushort_t*)(ws + off); off += (size_t)512 * 512 * 2;
  ushort_t* qkv_raw  = (ushort_t*)(ws + off); off += 3 * E1 * 2;
  ushort_t* q_bf     = (ushort_t*)(ws + off); off += E1 * 2;
  ushort_t* qaug     = (ushort_t*)(ws + off); off += (size_t)BB * NHH * NQ * AUG * 2;
  ushort_t* kaug     = (ushort_t*)(ws + off); off += (size_t)BB * NHH * NKV * AUG * 2;
  ushort_t* v_bf     = (ushort_t*)(ws + off); off += (size_t)BB * NHH * NKV * HDIM * 2;
  ushort_t* v_t      = (ushort_t*)(ws + off); off += (size_t)64 * 64 * VTP * 2;
  ushort_t* attn_bf  = qkv_raw;   // reuse (raw consumed by pools before attn)

  // 0) casts to bf16
  cast_bf16_kernel<<<(MROWS * 512 / 4 + 255) / 256, 256, 0, stream>>>(x, x_bf, MROWS * 512 / 4);
  cast_bf16_kernel<<<768, 256, 0, stream>>>(qkv_w, qkvw_bf, 1536 * 512 / 4);
  cast_bf16_kernel<<<256, 256, 0, stream>>>(proj_w, projw_bf, 512 * 512 / 4);

  // 1) QKV GEMM (BN=256, glds staging) -> qkv_raw scatter
  mfma_gemm_glds<0><<<dim3(6, 197), 512, 0, stream>>>(
      x_bf, qkvw_bf, qkv_b, (void*)qkv_raw, MROWS);

  // 2) pool + LN
  pool_ln_kernel<1><<<(64 * NQ) / 4,  256, 0, stream>>>(qkv_raw,          q_bf, qaug, pool_q_w, lnq_w, lnq_b, 1, 56, NQ);
  pool_ln_kernel<2><<<(64 * NKV) / 4, 256, 0, stream>>>(qkv_raw + E1,     kaug, nullptr, pool_k_w, lnk_w, lnk_b, 2, 28, NKV);
  pool_ln_kernel<0><<<(64 * NKV) / 4, 256, 0, stream>>>(qkv_raw + 2 * E1, v_bf, nullptr, pool_v_w, lnv_w, lnv_b, 2, 28, NKV);

  // 2b) V -> V^T
  transpose_v_kernel<<<dim3(13, 64), 256, 0, stream>>>(v_bf, v_t);

  // 3) rel bias via MFMA -> scatter bf16 into qaug[64:120]
  relbias_mfma_kernel<<<dim3(14, 56, 2), 256, 0, stream>>>(q_bf, rel_pos_h, rel_pos_w, qaug);

  // 4) flash attention (r12-proven) -> bf16 (B,N,512)
  attn_mfma32_kernel<<<dim3(25, 64), 256, 0, stream>>>(qaug, kaug, q_bf, v_t, attn_bf);

  // 5) proj GEMM (BN=256, glds staging) -> d_out f32
  mfma_gemm_glds<1><<<dim3(2, 197), 512, 0, stream>>>(
      attn_bf, projw_bf, proj_b, d_out, MROWS);
}

// Round 15
// 447.427 us; speedup vs baseline: 1.0310x; 1.0310x over previous
//
#include <hip/hip_runtime.h>
#include <hip/hip_bf16.h>
#include <cstdint>
#include <cstddef>

#define BB 8
#define NHH 8
#define NQ 3137      // 56*56+1
#define NKV 785      // 28*28+1
#define HDIM 64
#define AUG 128      // augmented channel count (64 q/k + 28 h + 28 w + 8 pad)
#define MROWS (BB*NQ)   // 25096
#define SCALE 0.125f
#define VTP 832         // padded v^T row length

typedef unsigned short ushort_t;
typedef __attribute__((ext_vector_type(8))) short s16x8;   // 8 bf16 (4 VGPR)
typedef __attribute__((ext_vector_type(4))) float f32x4;
typedef __attribute__((ext_vector_type(16))) float f32x16;

__device__ __forceinline__ float bf2f(ushort_t u) {
  union { unsigned int i; float f; } v; v.i = ((unsigned int)u) << 16; return v.f;
}
__device__ __forceinline__ ushort_t f2bf(float f) {
  union { float f; unsigned int i; } v; v.f = f;
  unsigned int r = v.i + 0x7fffu + ((v.i >> 16) & 1u);   // RNE
  return (ushort_t)(r >> 16);
}
__device__ __forceinline__ unsigned int cvt_pk_bf16(float lo, float hi) {
  unsigned int r;
  asm("v_cvt_pk_bf16_f32 %0, %1, %2" : "=v"(r) : "v"(lo), "v"(hi));
  return r;
}
// swizzled 16B fragment read, 128B rows (8 slots)
__device__ __forceinline__ s16x8 lds_frag8(const ushort_t* base, int row, int slot) {
  const char* p = (const char*)base + row * 128 + (((slot ^ (row & 7)) & 7) << 4);
  return *(const s16x8*)p;
}
// swizzled 16B fragment read, 256B rows (16 slots)
__device__ __forceinline__ s16x8 lds_frag16(const ushort_t* base, int row, int slot) {
  const char* p = (const char*)base + row * 256 + (((slot ^ (row & 15)) & 15) << 4);
  return *(const s16x8*)p;
}

// ---------------------------------------------------------------------------
// f32 -> bf16 cast, 4 elems/thread (all sizes are multiples of 4)
// ---------------------------------------------------------------------------
__global__ __launch_bounds__(256) void cast_bf16_kernel(
    const float* __restrict__ in, ushort_t* __restrict__ outp, int n4) {
  const int i = blockIdx.x * 256 + threadIdx.x;
  if (i >= n4) return;
  const float4 v = ((const float4*)in)[i];
  uint2 o;
  o.x = cvt_pk_bf16(v.x, v.y);
  o.y = cvt_pk_bf16(v.z, v.w);
  *(uint2*)(outp + (size_t)i * 4) = o;
}

// ---------------------------------------------------------------------------
// bf16 MFMA GEMM with global_load_lds staging (r11/r12-proven).
// C = A(M,512) @ W(N,512)^T + bias.  128x128 tile, BK=64, 4 waves.
// ---------------------------------------------------------------------------
template<int EPI>
__global__ __launch_bounds__(256) void mfma_gemm_glds(
    const ushort_t* __restrict__ A, const ushort_t* __restrict__ W,
    const float* __restrict__ bias, void* __restrict__ outp, int M) {
  __shared__ ushort_t As[128 * 64];   // 16 KB, 128 rows x 128B
  __shared__ ushort_t Bs[128 * 64];
  const int tid = threadIdx.x;
  const int l = tid & 63, w = tid >> 6;
  const int wr = w >> 1, wc = w & 1;
  const int lrow = l & 15, lk = l >> 4;
  const int m0 = blockIdx.y * 128, n0 = blockIdx.x * 128;
  const int lr8 = l >> 3;
  const int swzch = ((l & 7) ^ lr8) * 8;
  f32x4 acc[4][4];
  #pragma unroll
  for (int i = 0; i < 4; ++i) {
    #pragma unroll
    for (int j = 0; j < 4; ++j) acc[i][j] = (f32x4){0.f, 0.f, 0.f, 0.f};
  }
  for (int k0 = 0; k0 < 512; k0 += 64) {
    __syncthreads();   // previous k-step's frag reads done
    #pragma unroll
    for (int j = 0; j < 4; ++j) {
      const int rb = (w * 4 + j) * 8 + lr8;
      int mA = m0 + rb; if (mA > M - 1) mA = M - 1;
      const ushort_t* sa = A + (size_t)mA * 512 + k0 + swzch;
      const ushort_t* sb = W + (size_t)(n0 + rb) * 512 + k0 + swzch;
      __builtin_amdgcn_global_load_lds((void*)sa, (void*)(As + (w * 4 + j) * 512), 16, 0, 0);
      __builtin_amdgcn_global_load_lds((void*)sb, (void*)(Bs + (w * 4 + j) * 512), 16, 0, 0);
    }
    __syncthreads();   // drains vmcnt(0); tile published
    #pragma unroll
    for (int sub = 0; sub < 2; ++sub) {
      s16x8 af[4], bfr[4];
      #pragma unroll
      for (int mi = 0; mi < 4; ++mi) {
        const int r = wr * 64 + mi * 16 + lrow;
        const int slot = (sub * 4 + lk) ^ (r & 7);
        af[mi] = *(const s16x8*)(As + r * 64 + slot * 8);
      }
      #pragma unroll
      for (int ni = 0; ni < 4; ++ni) {
        const int r = wc * 64 + ni * 16 + lrow;
        const int slot = (sub * 4 + lk) ^ (r & 7);
        bfr[ni] = *(const s16x8*)(Bs + r * 64 + slot * 8);
      }
      #pragma unroll
      for (int mi = 0; mi < 4; ++mi) {
        #pragma unroll
        for (int ni = 0; ni < 4; ++ni)
          acc[mi][ni] = __builtin_amdgcn_mfma_f32_16x16x32_bf16(
              af[mi], bfr[ni], acc[mi][ni], 0, 0, 0);
      }
    }
  }
  #pragma unroll
  for (int mi = 0; mi < 4; ++mi) {
    #pragma unroll
    for (int r = 0; r < 4; ++r) {
      const int m = m0 + wr * 64 + mi * 16 + 4 * lk + r;
      if (m >= M) continue;
      #pragma unroll
      for (int ni = 0; ni < 4; ++ni) {
        const int n = n0 + wc * 64 + ni * 16 + lrow;
        const float v = acc[mi][ni][r] + bias[n];
        if (EPI == 0) {
          const int which = n >> 9, y = (n >> 6) & 7, c = n & 63;
          const int b_ = m / NQ, tok = m - b_ * NQ;
          ((ushort_t*)outp)[((((size_t)which * BB + b_) * NHH + y) * NQ + tok) * HDIM + c] = f2bf(v);
        } else {
          ((float*)outp)[(size_t)m * 512 + n] = v;
        }
      }
    }
  }
}

// ---------------------------------------------------------------------------
// Depthwise 3x3 pool + LayerNorm over HD=64.  MODE 0: plain bf16 row (v).
// MODE 1: q -> q_bf (unscaled) + qaug[0:64]=q*SCALE, [64:128]=0.
// MODE 2: k -> kaug[0:64]=k, [64:120]=one-hot(kh,kw), [120:128]=0.
// ---------------------------------------------------------------------------
template<int MODE>
__global__ __launch_bounds__(256) void pool_ln_kernel(
    const ushort_t* __restrict__ in, ushort_t* __restrict__ out0,
    ushort_t* __restrict__ out1,
    const float* __restrict__ cw, const float* __restrict__ lnw,
    const float* __restrict__ lnb, int stride, int OW, int R) {
  const int tid = threadIdx.x;
  const int c = tid & 63;
  const int rid = blockIdx.x * 4 + (tid >> 6);
  const int by = rid / R;
  const int n = rid - by * R;
  const ushort_t* ibase = in + (size_t)by * NQ * HDIM;
  float val;
  if (n == 0) {
    val = bf2f(ibase[c]);
  } else {
    const int p = n - 1;
    const int ho = p / OW, wo = p - ho * OW;
    float s = 0.f;
    #pragma unroll
    for (int dh = 0; dh < 3; ++dh) {
      const int hh = ho * stride + dh - 1;
      if (hh < 0 || hh >= 56) continue;
      #pragma unroll
      for (int dw = 0; dw < 3; ++dw) {
        const int ww = wo * stride + dw - 1;
        if (ww < 0 || ww >= 56) continue;
        s += cw[c * 9 + dh * 3 + dw] * bf2f(ibase[(size_t)(1 + hh * 56 + ww) * HDIM + c]);
      }
    }
    val = s;
  }
  float sum = val, sq = val * val;
  #pragma unroll
  for (int off = 32; off > 0; off >>= 1) {
    sum += __shfl_xor(sum, off);
    sq  += __shfl_xor(sq,  off);
  }
  const float mean = sum * (1.f / 64.f);
  const float var  = sq * (1.f / 64.f) - mean * mean;
  const float rs = rsqrtf(var + 1e-6f);
  const float lno = (val - mean) * rs * lnw[c] + lnb[c];
  if (MODE == 0) {
    out0[(size_t)rid * HDIM + c] = f2bf(lno);
  } else if (MODE == 1) {
    out0[(size_t)rid * HDIM + c] = f2bf(lno);
    out1[(size_t)rid * AUG + c] = f2bf(lno * SCALE);
    out1[(size_t)rid * AUG + 64 + c] = 0;
  } else {
    out0[(size_t)rid * AUG + c] = f2bf(lno);
    ushort_t aug = 0;
    if (n >= 1) {
      const int p = n - 1;
      const int kh = p / 28, kw = p - 28 * kh;
      if (c < 28) { if (c == kh) aug = 0x3F80; }
      else if (c < 56) { if (c - 28 == kw) aug = 0x3F80; }
    }
    out0[(size_t)rid * AUG + 64 + c] = aug;
  }
}

// ---------------------------------------------------------------------------
// V (row-major per head) -> V^T (64 channels x VTP cols), zero-padded cols.
// ---------------------------------------------------------------------------
__global__ __launch_bounds__(256) void transpose_v_kernel(
    const ushort_t* __restrict__ vin, ushort_t* __restrict__ vtout) {
  __shared__ ushort_t T[64][65];
  const int tid = threadIdx.x;
  const int by = blockIdx.y;
  const int n0 = blockIdx.x * 64;
  #pragma unroll
  for (int half = 0; half < 2; ++half) {
    const int idx = tid + half * 256;
    const int r = idx >> 3, s = idx & 7;
    const int n = n0 + r;
    uint4 d = make_uint4(0u, 0u, 0u, 0u);
    if (n < NKV) d = *(const uint4*)(vin + ((size_t)by * NKV + n) * HDIM + s * 8);
    const ushort_t* dp = (const ushort_t*)&d;
    #pragma unroll
    for (int e = 0; e < 8; ++e) T[r][s * 8 + e] = dp[e];
  }
  __syncthreads();
  #pragma unroll
  for (int half = 0; half < 2; ++half) {
    const int idx = tid + half * 256;
    const int c = idx >> 3, g = idx & 7;
    ushort_t pk[8];
    #pragma unroll
    for (int e = 0; e < 8; ++e) pk[e] = T[g * 8 + e][c];
    *(uint4*)(vtout + ((size_t)by * 64 + c) * VTP + n0 + g * 8) = *(const uint4*)pk;
  }
}

// ---------------------------------------------------------------------------
// MFMA rel-bias -> scatter bf16 directly into qaug channels 64+mode*28+kh.
// ---------------------------------------------------------------------------
__global__ __launch_bounds__(256) void relbias_mfma_kernel(
    const ushort_t* __restrict__ qb, const float* __restrict__ rph,
    const float* __restrict__ rpw, ushort_t* __restrict__ qaug) {
  const int tid = threadIdx.x;
  const int l = tid & 63, w = tid >> 6;
  const int lrow = l & 15, lk = l >> 4;
  const int hw = blockIdx.y;
  const int mode = blockIdx.z;
  const int r0 = blockIdx.x * 256 + w * 64;
  const float* tab = mode ? rpw : rph;
  s16x8 bfr[2][2];
  #pragma unroll
  for (int ni = 0; ni < 2; ++ni) {
    const int kh = ni * 16 + lrow;
    int trow = hw - 2 * kh + 54;
    if (trow < 0) trow = 0;
    const float* tr = tab + (size_t)trow * 64 + lk * 8;
    #pragma unroll
    for (int k0 = 0; k0 < 2; ++k0) {
      const float4 t0 = *(const float4*)(tr + k0 * 32);
      const float4 t1 = *(const float4*)(tr + k0 * 32 + 4);
      s16x8 bb;
      bb[0] = (short)f2bf(t0.x); bb[1] = (short)f2bf(t0.y);
      bb[2] = (short)f2bf(t0.z); bb[3] = (short)f2bf(t0.w);
      bb[4] = (short)f2bf(t1.x); bb[5] = (short)f2bf(t1.y);
      bb[6] = (short)f2bf(t1.z); bb[7] = (short)f2bf(t1.w);
      bfr[ni][k0] = bb;
    }
  }
  s16x8 af[4][2];
  #pragma unroll
  for (int mi = 0; mi < 4; ++mi) {
    const int rA = r0 + mi * 16 + lrow;
    const int by = rA / 56, oth = rA - 56 * by;
    const int tok = mode ? (1 + oth * 56 + hw) : (1 + hw * 56 + oth);
    const ushort_t* qp = qb + ((size_t)by * NQ + tok) * HDIM + lk * 8;
    af[mi][0] = *(const s16x8*)(qp);
    af[mi][1] = *(const s16x8*)(qp + 32);
  }
  f32x4 acc[4][2];
  #pragma unroll
  for (int mi = 0; mi < 4; ++mi) {
    #pragma unroll
    for (int ni = 0; ni < 2; ++ni) acc[mi][ni] = (f32x4){0.f, 0.f, 0.f, 0.f};
  }
  #pragma unroll
  for (int k0 = 0; k0 < 2; ++k0) {
    #pragma unroll
    for (int mi = 0; mi < 4; ++mi) {
      #pragma unroll
      for (int ni = 0; ni < 2; ++ni)
        acc[mi][ni] = __builtin_amdgcn_mfma_f32_16x16x32_bf16(
            af[mi][k0], bfr[ni][k0], acc[mi][ni], 0, 0, 0);
    }
  }
  const int augofs = 64 + mode * 28;
  #pragma unroll
  for (int mi = 0; mi < 4; ++mi) {
    #pragma unroll
    for (int r = 0; r < 4; ++r) {
      const int row = r0 + mi * 16 + 4 * lk + r;
      const int by = row / 56, oth = row - 56 * by;
      const int tok = 1 + (mode ? (oth * 56 + hw) : (hw * 56 + oth));
      ushort_t* orow = qaug + ((size_t)by * NQ + tok) * AUG + augofs;
      #pragma unroll
      for (int ni = 0; ni < 2; ++ni) {
        const int kh = ni * 16 + lrow;
        if (kh < 28) orow[kh] = f2bf(acc[mi][ni][r]);
      }
    }
  }
}

// ---------------------------------------------------------------------------
// Flash attention (r12-proven, 148us): glds double-buffered K/V staging,
// ONE barrier per k-tile.  32x32 MFMA swapped, bias via aug channels,
// defer-max + tree reductions, in-place exp.
// ---------------------------------------------------------------------------
__global__ __launch_bounds__(256) void attn_mfma32_kernel(
    const ushort_t* __restrict__ qaug, const ushort_t* __restrict__ kaug,
    const ushort_t* __restrict__ qb, const ushort_t* __restrict__ vt,
    ushort_t* __restrict__ outp) {
  __shared__ ushort_t Kl[2][64 * 128];   // 2 x 16 KB (64 rows x 256B)
  __shared__ ushort_t Vl[2][64 * 64];    // 2 x 8 KB  (64 rows x 128B)
  const int tid = threadIdx.x;
  const int l = tid & 63, w = tid >> 6;
  const int h = l >> 5, q5 = l & 31;
  const int by = blockIdx.y;
  const int qt0 = blockIdx.x * 128;
  const int qloc = w * 32 + q5;
  const int qglob = qt0 + qloc;
  const int qcl = qglob < NQ ? qglob : NQ - 1;
  const ushort_t* qrow = qaug + ((size_t)by * NQ + qcl) * AUG;
  s16x8 qf[8];
  #pragma unroll
  for (int cb = 0; cb < 8; ++cb)
    qf[cb] = *(const s16x8*)(qrow + cb * 16 + h * 8);
  f32x16 ot0, ot1;
  #pragma unroll
  for (int i = 0; i < 16; ++i) { ot0[i] = 0.f; ot1[i] = 0.f; }
  float mr = -1e30f, lr = 0.f;
  const ushort_t* kab = kaug + (size_t)by * NKV * AUG;
  const ushort_t* vtb = vt + (size_t)by * 64 * VTP;
  const int krloc = l >> 4;                 // 0..3
  const int vrloc = l >> 3;                 // 0..7
  auto issue_tile = [&](int it_, int buf) {
    const int j0 = it_ * 64;
    ushort_t* Kb = &Kl[buf][0];
    ushort_t* Vb = &Vl[buf][0];
    #pragma unroll
    for (int jj = 0; jj < 4; ++jj) {
      const int r0 = w * 16 + jj * 4;
      const int rloc = r0 + krloc;
      int jg = j0 + rloc; if (jg > NKV - 1) jg = NKV - 1;
      const int sch = ((l & 15) ^ (rloc & 15)) * 8;
      const ushort_t* src = kab + (size_t)jg * AUG + sch;
      __builtin_amdgcn_global_load_lds((void*)src, (void*)(Kb + r0 * 128), 16, 0, 0);
    }
    #pragma unroll
    for (int jj = 0; jj < 2; ++jj) {
      const int r0 = w * 16 + jj * 8;
      const int crow = r0 + vrloc;
      const int sch = ((l & 7) ^ (crow & 7)) * 8;
      const ushort_t* src = vtb + (size_t)crow * VTP + j0 + sch;
      __builtin_amdgcn_global_load_lds((void*)src, (void*)(Vb + r0 * 64), 16, 0, 0);
    }
  };
  issue_tile(0, 0);
  __syncthreads();
  #pragma unroll 1
  for (int it = 0; it < 13; ++it) {
    const int cur = it & 1;
    const ushort_t* Kc = &Kl[cur][0];
    const ushort_t* Vc = &Vl[cur][0];
    if (it < 12) issue_tile(it + 1, cur ^ 1);
    f32x16 st0, st1;
    #pragma unroll
    for (int i = 0; i < 16; ++i) { st0[i] = 0.f; st1[i] = 0.f; }
    __builtin_amdgcn_s_setprio(1);
    #pragma unroll
    for (int cb = 0; cb < 8; ++cb) {
      st0 = __builtin_amdgcn_mfma_f32_32x32x16_bf16(
          lds_frag16(Kc, q5, cb * 2 + h), qf[cb], st0, 0, 0, 0);
      st1 = __builtin_amdgcn_mfma_f32_32x32x16_bf16(
          lds_frag16(Kc, 32 + q5, cb * 2 + h), qf[cb], st1, 0, 0, 0);
    }
    __builtin_amdgcn_s_setprio(0);
    if (it == 12) {
      #pragma unroll
      for (int r = 0; r < 16; ++r) {
        const int klocal = (r & 3) + 8 * (r >> 2) + 4 * h;
        if (768 + klocal >= NKV) st0[r] = -1e30f;
        st1[r] = -1e30f;
      }
    }
    float tm[16];
    #pragma unroll
    for (int r = 0; r < 16; ++r) tm[r] = fmaxf(st0[r], st1[r]);
    #pragma unroll
    for (int s = 8; s > 0; s >>= 1) {
      #pragma unroll
      for (int r = 0; r < 8; ++r)
        if (r < s) tm[r] = fmaxf(tm[r], tm[r + s]);
    }
    float mloc = fmaxf(tm[0], __shfl_xor(tm[0], 32));
    if (!__all(mloc <= mr + 8.f)) {
      const float mn = fmaxf(mr, mloc);
      const float sc = __expf(mr - mn);
      mr = mn;
      lr *= sc;
      #pragma unroll
      for (int i = 0; i < 16; ++i) { ot0[i] *= sc; ot1[i] *= sc; }
    }
    float ts[16];
    #pragma unroll
    for (int r = 0; r < 16; ++r) {
      st0[r] = __expf(st0[r] - mr);
      st1[r] = __expf(st1[r] - mr);
      ts[r] = st0[r] + st1[r];
    }
    #pragma unroll
    for (int s = 8; s > 0; s >>= 1) {
      #pragma unroll
      for (int r = 0; r < 8; ++r)
        if (r < s) ts[r] += ts[r + s];
    }
    lr += ts[0] + __shfl_xor(ts[0], 32);
    auto pvstep = [&](const f32x16& pv, int kt) {
      #pragma unroll
      for (int kbk = 0; kbk < 2; ++kbk) {
        const unsigned int pk01 = cvt_pk_bf16(pv[kbk * 8 + 0], pv[kbk * 8 + 1]);
        const unsigned int pk23 = cvt_pk_bf16(pv[kbk * 8 + 2], pv[kbk * 8 + 3]);
        const unsigned int pk45 = cvt_pk_bf16(pv[kbk * 8 + 4], pv[kbk * 8 + 5]);
        const unsigned int pk67 = cvt_pk_bf16(pv[kbk * 8 + 6], pv[kbk * 8 + 7]);
        const unsigned int sA = (unsigned int)__shfl_xor((int)pk01, 32);
        const unsigned int sB = (unsigned int)__shfl_xor((int)pk45, 32);
        const unsigned int sC = (unsigned int)__shfl_xor((int)pk23, 32);
        const unsigned int sD = (unsigned int)__shfl_xor((int)pk67, 32);
        int4 fw;
        fw.x = (int)(h ? sB : pk01);
        fw.y = (int)(h ? sD : pk23);
        fw.z = (int)(h ? pk45 : sA);
        fw.w = (int)(h ? pk67 : sC);
        s16x8 pf;
        __builtin_memcpy(&pf, &fw, 16);
        const int slot = kt * 4 + kbk * 2 + h;
        __builtin_amdgcn_s_setprio(1);
        ot0 = __builtin_amdgcn_mfma_f32_32x32x16_bf16(
            lds_frag8(Vc, q5, slot), pf, ot0, 0, 0, 0);
        ot1 = __builtin_amdgcn_mfma_f32_32x32x16_bf16(
            lds_frag8(Vc, 32 + q5, slot), pf, ot1, 0, 0, 0);
        __builtin_amdgcn_s_setprio(0);
      }
    };
    pvstep(st0, 0);
    pvstep(st1, 1);
    __syncthreads();
  }
  const float inv = 1.f / lr;
  if (qglob < NQ) {
    const int b_ = by >> 3, y_ = by & 7;
    ushort_t* obase = outp + ((size_t)b_ * NQ + qglob) * 512 + (size_t)y_ * 64;
    const ushort_t* rbase = qb + ((size_t)by * NQ + qglob) * HDIM;
    #pragma unroll
    for (int ch = 0; ch < 2; ++ch) {
      #pragma unroll
      for (int rg = 0; rg < 4; ++rg) {
        const int c0 = ch * 32 + 8 * rg + 4 * h;
        float vv[4];
        #pragma unroll
        for (int e = 0; e < 4; ++e)
          vv[e] = (ch ? ot1[rg * 4 + e] : ot0[rg * 4 + e]) * inv;
        if (qglob > 0) {
          #pragma unroll
          for (int e = 0; e < 4; ++e) vv[e] += bf2f(rbase[c0 + e]);
        }
        ushort_t pk[4] = { f2bf(vv[0]), f2bf(vv[1]), f2bf(vv[2]), f2bf(vv[3]) };
        *(uint2*)(obase + c0) = *(const uint2*)pk;
      }
    }
  }
}

// ---------------------------------------------------------------------------
extern "C" void kernel_launch(void* const* d_in, const int* in_sizes, int n_in,
                              void* d_out, int out_size, void* d_ws, size_t ws_size,
                              hipStream_t stream) {
  const float* x        = (const float*)d_in[0];
  const float* qkv_w    = (const float*)d_in[1];
  const float* qkv_b    = (const float*)d_in[2];
  const float* proj_w   = (const float*)d_in[3];
  const float* proj_b   = (const float*)d_in[4];
  const float* pool_q_w = (const float*)d_in[5];
  const float* pool_k_w = (const float*)d_in[6];
  const float* pool_v_w = (const float*)d_in[7];
  const float* lnq_w    = (const float*)d_in[8];
  const float* lnq_b    = (const float*)d_in[9];
  const float* lnk_w    = (const float*)d_in[10];
  const float* lnk_b    = (const float*)d_in[11];
  const float* lnv_w    = (const float*)d_in[12];
  const float* lnv_b    = (const float*)d_in[13];
  const float* rel_pos_h = (const float*)d_in[14];
  const float* rel_pos_w = (const float*)d_in[15];

  constexpr size_t E1 = (size_t)BB * NHH * NQ * HDIM;   // 12,849,152
  char* ws = (char*)d_ws;
  size_t off = 0;
  ushort_t* x_bf     = (ushort_t*)(ws + off); off += (size_t)MROWS * 512 * 2;
  ushort_t* qkvw_bf  = (ushort_t*)(ws + off); off += (size_t)1536 * 512 * 2;
  ushort_t* projw_bf = (ushort_t*)(ws + off); off += (size_t)512 * 512 * 2;
  ushort_t* qkv_raw  = (ushort_t*)(ws + off); off += 3 * E1 * 2;
  ushort_t* q_bf     = (ushort_t*)(ws + off); off += E1 * 2;
  ushort_t* qaug     = (ushort_t*)(ws + off); off += (size_t)BB * NHH * NQ * AUG * 2;
  ushort_t* kaug     = (ushort_t*)(ws + off); off += (size_t)BB * NHH * NKV * AUG * 2;
  ushort_t* v_bf     = (ushort_t*)(ws + off); off += (size_t)BB * NHH * NKV * HDIM * 2;
  ushort_t* v_t      = (ushort_t*)(ws + off); off += (size_t)64 * 64 * VTP * 2;
  ushort_t* attn_bf  = qkv_raw;   // reuse (raw consumed by pools before attn)

  // 0) casts to bf16
  cast_bf16_kernel<<<(MROWS * 512 / 4 + 255) / 256, 256, 0, stream>>>(x, x_bf, MROWS * 512 / 4);
  cast_bf16_kernel<<<768, 256, 0, stream>>>(qkv_w, qkvw_bf, 1536 * 512 / 4);
  cast_bf16_kernel<<<256, 256, 0, stream>>>(proj_w, projw_bf, 512 * 512 / 4);

  // 1) QKV GEMM (global_load_lds staging) -> qkv_raw scatter
  mfma_gemm_glds<0><<<dim3(12, 197), 256, 0, stream>>>(
      x_bf, qkvw_bf, qkv_b, (void*)qkv_raw, MROWS);

  // 2) pool + LN
  pool_ln_kernel<1><<<(64 * NQ) / 4,  256, 0, stream>>>(qkv_raw,          q_bf, qaug, pool_q_w, lnq_w, lnq_b, 1, 56, NQ);
  pool_ln_kernel<2><<<(64 * NKV) / 4, 256, 0, stream>>>(qkv_raw + E1,     kaug, nullptr, pool_k_w, lnk_w, lnk_b, 2, 28, NKV);
  pool_ln_kernel<0><<<(64 * NKV) / 4, 256, 0, stream>>>(qkv_raw + 2 * E1, v_bf, nullptr, pool_v_w, lnv_w, lnv_b, 2, 28, NKV);

  // 2b) V -> V^T
  transpose_v_kernel<<<dim3(13, 64), 256, 0, stream>>>(v_bf, v_t);

  // 3) rel bias via MFMA -> scatter bf16 into qaug[64:120]
  relbias_mfma_kernel<<<dim3(14, 56, 2), 256, 0, stream>>>(q_bf, rel_pos_h, rel_pos_w, qaug);

  // 4) flash attention (glds double-buffer, 1 barrier/iter) -> bf16 (B,N,512)
  attn_mfma32_kernel<<<dim3(25, 64), 256, 0, stream>>>(qaug, kaug, q_bf, v_t, attn_bf);

  // 5) proj GEMM (global_load_lds staging) -> d_out f32
  mfma_gemm_glds<1><<<dim3(4, 197), 256, 0, stream>>>(
      attn_bf, projw_bf, proj_b, d_out, MROWS);
}